// Round 2
// baseline (241.529 us; speedup 1.0000x reference)
//
#include <hip/hip_runtime.h>
#include <hip/hip_bf16.h>

typedef __bf16 bf16_t;
typedef __bf16 bf16x8 __attribute__((ext_vector_type(8)));
typedef __bf16 bf16x4 __attribute__((ext_vector_type(4)));
typedef float  f32x4  __attribute__((ext_vector_type(4)));

#define SEQ    2048
#define BATCH  2
#define NHEAD  16
#define HDIM   64
#define DMODEL 1024
#define WIN    256

// async global->LDS, 16B per lane. LDS dest is wave-uniform base + lane*16;
// our lane->address mapping is contiguous per wave, so per-lane pointers are
// consistent with the HW semantics. Generic->AS cast via uintptr (low 32 bits
// of a generic shared address are the LDS offset on gfx9+).
__device__ __forceinline__ void async_load16(const void* g, void* l) {
    __builtin_amdgcn_global_load_lds(
        (const __attribute__((address_space(1))) char*)(uintptr_t)g,
        (__attribute__((address_space(3))) char*)(uintptr_t)l, 16, 0, 0);
}

// ---------------------------------------------------------------------------
// Kernel 1: cast x (fp32) -> bf16, flat [4096][1024]
// ---------------------------------------------------------------------------
__global__ void cast_x_kernel(const float* __restrict__ x, bf16_t* __restrict__ xb, int n4) {
    int i = blockIdx.x * blockDim.x + threadIdx.x;
    if (i >= n4) return;
    float4 v = ((const float4*)x)[i];
    bf16x4 o;
    o[0] = (bf16_t)v.x; o[1] = (bf16_t)v.y; o[2] = (bf16_t)v.z; o[3] = (bf16_t)v.w;
    ((bf16x4*)xb)[i] = o;
}

// ---------------------------------------------------------------------------
// Kernel 2: transpose+cast the 4 weight matrices into Wt[4][1024][1024],
// Wt[sel][n][k] = W_sel[k][n]  (B^T layout so GEMM B-fragments are contiguous)
// ---------------------------------------------------------------------------
__global__ void transpose_w_kernel(const float* __restrict__ Wq, const float* __restrict__ Wk,
                                   const float* __restrict__ Wv, const float* __restrict__ Wo,
                                   bf16_t* __restrict__ Wt) {
    __shared__ float tile[32][33];
    const float* W = (blockIdx.z == 0) ? Wq : (blockIdx.z == 1) ? Wk : (blockIdx.z == 2) ? Wv : Wo;
    bf16_t* out = Wt + (size_t)blockIdx.z * DMODEL * DMODEL;
    int k0 = blockIdx.y * 32, n0 = blockIdx.x * 32;
    int tx = threadIdx.x, ty = threadIdx.y;  // block (32, 8)
#pragma unroll
    for (int i = 0; i < 4; i++)
        tile[ty + i * 8][tx] = W[(size_t)(k0 + ty + i * 8) * DMODEL + n0 + tx];
    __syncthreads();
#pragma unroll
    for (int i = 0; i < 4; i++)
        out[(size_t)(n0 + ty + i * 8) * DMODEL + k0 + tx] = (bf16_t)tile[tx][ty + i * 8];
}

// ---------------------------------------------------------------------------
// GEMM: C[M][N] = A[M][K] * Bt[N][K]^T, 128x128 tile, 256 thr = 4 waves,
// m97 structure: global_load_lds width-16 staging into unpadded [128][64] LDS.
// EPI 0: QKV scatter epilogue (Q scaled 0.125; K [B,H,S,64]; V^T [B,H,64,S])
// EPI 1: Out[mg][ng] = acc + bo[ng]  (fp32)
// ---------------------------------------------------------------------------
template <int EPI>
__global__ __launch_bounds__(256) void gemm_bt_kernel(
    const bf16_t* __restrict__ A, const bf16_t* __restrict__ Bt,
    bf16_t* __restrict__ Qb, bf16_t* __restrict__ Kb, bf16_t* __restrict__ Vt,
    float* __restrict__ Out, const float* __restrict__ bo, int K) {
    __shared__ __attribute__((aligned(16))) bf16_t As[128][64];
    __shared__ __attribute__((aligned(16))) bf16_t Bs[128][64];
    const int tid = threadIdx.x;
    const int wave = tid >> 6, lane = tid & 63, quad = lane >> 4, l15 = lane & 15;
    const int wm = wave >> 1, wn = wave & 1;
    const int m0 = blockIdx.y * 128, n0 = blockIdx.x * 128;

    f32x4 acc[4][4] = {};

    for (int kt = 0; kt < K; kt += 64) {
#pragma unroll
        for (int i = 0; i < 4; i++) {
            int v = tid + i * 256;           // 1024 chunks of 16B per matrix
            int row = v >> 3, c8 = (v & 7) * 8;
            async_load16(A + (size_t)(m0 + row) * K + kt + c8, (char*)As + (size_t)v * 16);
            async_load16(Bt + (size_t)(n0 + row) * K + kt + c8, (char*)Bs + (size_t)v * 16);
        }
        __syncthreads();
#pragma unroll
        for (int kk = 0; kk < 64; kk += 32) {
            bf16x8 am[4], bn[4];
#pragma unroll
            for (int i = 0; i < 4; i++)
                am[i] = *(const bf16x8*)&As[wm * 64 + i * 16 + l15][kk + quad * 8];
#pragma unroll
            for (int j = 0; j < 4; j++)
                bn[j] = *(const bf16x8*)&Bs[wn * 64 + j * 16 + l15][kk + quad * 8];
#pragma unroll
            for (int i = 0; i < 4; i++)
#pragma unroll
                for (int j = 0; j < 4; j++)
                    acc[i][j] = __builtin_amdgcn_mfma_f32_16x16x32_bf16(am[i], bn[j], acc[i][j], 0, 0, 0);
        }
        __syncthreads();
    }

#pragma unroll
    for (int i = 0; i < 4; i++)
#pragma unroll
        for (int j = 0; j < 4; j++)
#pragma unroll
            for (int r = 0; r < 4; r++) {
                int mg = m0 + wm * 64 + i * 16 + quad * 4 + r;
                int ng = n0 + wn * 64 + j * 16 + l15;
                float v = acc[i][j][r];
                if (EPI == 0) {
                    int sel = ng >> 10, nl = ng & 1023, h = nl >> 6, d = nl & 63;
                    int b = mg >> 11, s = mg & 2047;
                    size_t idx = ((size_t)((b * NHEAD + h) * SEQ) + s) * HDIM + d;
                    if (sel == 0)      Qb[idx] = (bf16_t)(v * 0.125f);
                    else if (sel == 1) Kb[idx] = (bf16_t)v;
                    else               Vt[((size_t)((b * NHEAD + h) * HDIM) + d) * SEQ + s] = (bf16_t)v;
                } else {
                    Out[(size_t)mg * DMODEL + ng] = v + bo[ng];
                }
            }
}

// ---------------------------------------------------------------------------
// Attention v2: no online softmax. Scores are bounded (|s| <= ||q||||k||/8 ~ 1.3),
// so p = exp(s) directly (masked -> 0). Denominator l = row-sum of P computed
// by MFMA with a ones B-fragment (same C-layout rows as O, no cross-lane ops).
// One block (256 thr = 4 waves) per (b, h, 64-query tile); wave owns 16 rows.
// ---------------------------------------------------------------------------
__global__ __launch_bounds__(256) void attn_kernel(
    const bf16_t* __restrict__ Qb, const bf16_t* __restrict__ Kb,
    const bf16_t* __restrict__ Vt, bf16_t* __restrict__ ctx) {
    __shared__ __attribute__((aligned(16))) bf16_t Plds[4][16][72];
    const int tid = threadIdx.x;
    const int wave = tid >> 6, lane = tid & 63, quad = lane >> 4, l15 = lane & 15;
    const int b = blockIdx.z, h = blockIdx.y, q0 = blockIdx.x * 64;
    const int qbase = q0 + wave * 16;

    const bf16_t* Qp = Qb + (size_t)(b * NHEAD + h) * SEQ * HDIM;
    const bf16_t* Kp = Kb + (size_t)(b * NHEAD + h) * SEQ * HDIM;
    const bf16_t* Vp = Vt + (size_t)(b * NHEAD + h) * HDIM * SEQ;

    // Q A-fragments: lane holds Q[qbase + l15][quad*8 .. +8] (two 32-wide k chunks)
    bf16x8 qa0 = *(const bf16x8*)(Qp + (size_t)(qbase + l15) * HDIM + quad * 8);
    bf16x8 qa1 = *(const bf16x8*)(Qp + (size_t)(qbase + l15) * HDIM + 32 + quad * 8);

    bf16x8 ones;
#pragma unroll
    for (int j = 0; j < 8; j++) ones[j] = (bf16_t)1.0f;

    f32x4 O[4] = {};
    f32x4 lacc = {};

    const int qt = q0 >> 6;
    const int t0 = (qt - 4 > 0) ? qt - 4 : 0;
    const int t1 = (qt + 4 < SEQ / 64 - 1) ? qt + 4 : SEQ / 64 - 1;

    for (int kt = t0; kt <= t1; kt++) {
        const int k0 = kt * 64;
        f32x4 s[4];
#pragma unroll
        for (int c = 0; c < 4; c++) {
            const bf16_t* kr = Kp + (size_t)(k0 + c * 16 + l15) * HDIM;
            bf16x8 kb0 = *(const bf16x8*)(kr + quad * 8);
            bf16x8 kb1 = *(const bf16x8*)(kr + 32 + quad * 8);
            f32x4 a = {};
            a = __builtin_amdgcn_mfma_f32_16x16x32_bf16(qa0, kb0, a, 0, 0, 0);
            a = __builtin_amdgcn_mfma_f32_16x16x32_bf16(qa1, kb1, a, 0, 0, 0);
            s[c] = a;
        }
        // band mask — only edge tiles (|dt| == 4) can have out-of-window pairs
        const int dt = kt - qt;
        const bool edge = (dt <= -4 || dt >= 4);
        // p = exp(s), write P (bf16) to this wave's private LDS strip (C->A layout)
#pragma unroll
        for (int c = 0; c < 4; c++)
#pragma unroll
            for (int r = 0; r < 4; r++) {
                float sv = s[c][r];
                if (edge) {
                    int i = qbase + quad * 4 + r;
                    int j = k0 + c * 16 + l15;
                    int dd = i - j; dd = (dd < 0) ? -dd : dd;
                    if (dd > WIN) sv = -1e30f;
                }
                Plds[wave][quad * 4 + r][c * 16 + l15] = (bf16_t)__expf(sv);
            }
        bf16x8 pa0 = *(const bf16x8*)&Plds[wave][l15][quad * 8];
        bf16x8 pa1 = *(const bf16x8*)&Plds[wave][l15][32 + quad * 8];
        // denominator: row-sum via ones-MFMA (every col of lacc = row sum)
        lacc = __builtin_amdgcn_mfma_f32_16x16x32_bf16(pa0, ones, lacc, 0, 0, 0);
        lacc = __builtin_amdgcn_mfma_f32_16x16x32_bf16(pa1, ones, lacc, 0, 0, 0);
#pragma unroll
        for (int d = 0; d < 4; d++) {
            const bf16_t* vr = Vp + (size_t)(d * 16 + l15) * SEQ + k0;
            bf16x8 vb0 = *(const bf16x8*)(vr + quad * 8);
            bf16x8 vb1 = *(const bf16x8*)(vr + 32 + quad * 8);
            O[d] = __builtin_amdgcn_mfma_f32_16x16x32_bf16(pa0, vb0, O[d], 0, 0, 0);
            O[d] = __builtin_amdgcn_mfma_f32_16x16x32_bf16(pa1, vb1, O[d], 0, 0, 0);
        }
    }

#pragma unroll
    for (int r = 0; r < 4; r++) {
        float inv = 1.0f / lacc[r];
        int i = qbase + quad * 4 + r;
#pragma unroll
        for (int d = 0; d < 4; d++) {
            float v = O[d][r] * inv;
            ctx[((size_t)(b * SEQ + i)) * DMODEL + h * HDIM + d * 16 + l15] = (bf16_t)v;
        }
    }
}

// ---------------------------------------------------------------------------
extern "C" void kernel_launch(void* const* d_in, const int* in_sizes, int n_in,
                              void* d_out, int out_size, void* d_ws, size_t ws_size,
                              hipStream_t stream) {
    const float* x  = (const float*)d_in[0];
    const float* Wq = (const float*)d_in[1];
    const float* Wk = (const float*)d_in[2];
    const float* Wv = (const float*)d_in[3];
    const float* Wo = (const float*)d_in[4];
    const float* bo = (const float*)d_in[5];
    float* out = (float*)d_out;

    const size_t MTOK = (size_t)BATCH * SEQ;          // 4096
    bf16_t* xb  = (bf16_t*)d_ws;                      // 4096*1024
    bf16_t* Wt  = xb + MTOK * DMODEL;                 // 4*1024*1024 (q,k,v,o transposed)
    bf16_t* Qb  = Wt + (size_t)4 * DMODEL * DMODEL;   // [B,H,S,64]
    bf16_t* Kb  = Qb + MTOK * DMODEL;                 // [B,H,S,64]
    bf16_t* Vt  = Kb + MTOK * DMODEL;                 // [B,H,64,S]
    bf16_t* ctx = Vt + MTOK * DMODEL;                 // [4096][1024]

    cast_x_kernel<<<dim3((MTOK * DMODEL / 4 + 255) / 256), dim3(256), 0, stream>>>(
        x, xb, (int)(MTOK * DMODEL / 4));
    transpose_w_kernel<<<dim3(32, 32, 4), dim3(32, 8), 0, stream>>>(Wq, Wk, Wv, Wo, Wt);
    // QKV: M=4096, N=3072, K=1024
    gemm_bt_kernel<0><<<dim3(24, 32), dim3(256), 0, stream>>>(
        xb, Wt, Qb, Kb, Vt, nullptr, nullptr, DMODEL);
    attn_kernel<<<dim3(SEQ / 64, NHEAD, BATCH), dim3(256), 0, stream>>>(Qb, Kb, Vt, ctx);
    // Out: M=4096, N=1024, K=1024
    gemm_bt_kernel<1><<<dim3(8, 32), dim3(256), 0, stream>>>(
        ctx, Wt + (size_t)3 * DMODEL * DMODEL, nullptr, nullptr, nullptr, out, bo, DMODEL);
}

// Round 3
// 179.044 us; speedup vs baseline: 1.3490x; 1.3490x over previous
//
#include <hip/hip_runtime.h>
#include <hip/hip_bf16.h>

typedef __bf16 bf16_t;
typedef __bf16 bf16x8 __attribute__((ext_vector_type(8)));
typedef __bf16 bf16x4 __attribute__((ext_vector_type(4)));
typedef float  f32x4  __attribute__((ext_vector_type(4)));

#define SEQ    2048
#define BATCH  2
#define NHEAD  16
#define HDIM   64
#define DMODEL 1024
#define WIN    256

// async global->LDS, 16B per lane (dest = wave-uniform base + lane*16).
__device__ __forceinline__ void async_load16(const void* g, void* l) {
    __builtin_amdgcn_global_load_lds(
        (const __attribute__((address_space(1))) char*)(uintptr_t)g,
        (__attribute__((address_space(3))) char*)(uintptr_t)l, 16, 0, 0);
}

// ---------------------------------------------------------------------------
// Kernel 1: cast x (fp32) -> bf16, flat [4096][1024]
// ---------------------------------------------------------------------------
__global__ void cast_x_kernel(const float* __restrict__ x, bf16_t* __restrict__ xb, int n4) {
    int i = blockIdx.x * blockDim.x + threadIdx.x;
    if (i >= n4) return;
    float4 v = ((const float4*)x)[i];
    bf16x4 o;
    o[0] = (bf16_t)v.x; o[1] = (bf16_t)v.y; o[2] = (bf16_t)v.z; o[3] = (bf16_t)v.w;
    ((bf16x4*)xb)[i] = o;
}

// ---------------------------------------------------------------------------
// Kernel 2: transpose+cast weights into Wt[4][1024][1024] (B^T layout)
// ---------------------------------------------------------------------------
__global__ void transpose_w_kernel(const float* __restrict__ Wq, const float* __restrict__ Wk,
                                   const float* __restrict__ Wv, const float* __restrict__ Wo,
                                   bf16_t* __restrict__ Wt) {
    __shared__ float tile[32][33];
    const float* W = (blockIdx.z == 0) ? Wq : (blockIdx.z == 1) ? Wk : (blockIdx.z == 2) ? Wv : Wo;
    bf16_t* out = Wt + (size_t)blockIdx.z * DMODEL * DMODEL;
    int k0 = blockIdx.y * 32, n0 = blockIdx.x * 32;
    int tx = threadIdx.x, ty = threadIdx.y;  // block (32, 8)
#pragma unroll
    for (int i = 0; i < 4; i++)
        tile[ty + i * 8][tx] = W[(size_t)(k0 + ty + i * 8) * DMODEL + n0 + tx];
    __syncthreads();
#pragma unroll
    for (int i = 0; i < 4; i++)
        out[(size_t)(n0 + ty + i * 8) * DMODEL + k0 + tx] = (bf16_t)tile[tx][ty + i * 8];
}

// ---------------------------------------------------------------------------
// GEMM: C = A * Bt^T, 128x128 tile, global_load_lds staging with XOR chunk
// swizzle: element (row, 8-elem chunk c) lives at LDS chunk row*8 + (c^(row&7)).
// Staging (lane v -> LDS chunk v) reads global chunk (v&7)^(row&7); fragment
// ds_read_b128 then hits all 32 banks 2-way (free) instead of 16-way.
// ---------------------------------------------------------------------------
template <int EPI>
__global__ __launch_bounds__(256) void gemm_bt_kernel(
    const bf16_t* __restrict__ A, const bf16_t* __restrict__ Bt,
    bf16_t* __restrict__ Qb, bf16_t* __restrict__ Kb, bf16_t* __restrict__ Vt,
    float* __restrict__ Out, const float* __restrict__ bo, int K) {
    __shared__ __attribute__((aligned(16))) bf16_t As[128 * 64];
    __shared__ __attribute__((aligned(16))) bf16_t Bs[128 * 64];
    const int tid = threadIdx.x;
    const int wave = tid >> 6, lane = tid & 63, quad = lane >> 4, l15 = lane & 15;
    const int wm = wave >> 1, wn = wave & 1;
    const int m0 = blockIdx.y * 128, n0 = blockIdx.x * 128;

    f32x4 acc[4][4] = {};

    for (int kt = 0; kt < K; kt += 64) {
#pragma unroll
        for (int i = 0; i < 4; i++) {
            int v = tid + i * 256;           // 1024 chunks of 16B per matrix
            int row = v >> 3, c = (v & 7) ^ (row & 7);
            async_load16(A + (size_t)(m0 + row) * K + kt + c * 8, (char*)As + (size_t)v * 16);
            async_load16(Bt + (size_t)(n0 + row) * K + kt + c * 8, (char*)Bs + (size_t)v * 16);
        }
        __syncthreads();
#pragma unroll
        for (int kk = 0; kk < 64; kk += 32) {
            bf16x8 am[4], bn[4];
#pragma unroll
            for (int i = 0; i < 4; i++) {
                int row = wm * 64 + i * 16 + l15;
                int ch = ((kk >> 3) + quad) ^ (row & 7);
                am[i] = *(const bf16x8*)&As[row * 64 + ch * 8];
            }
#pragma unroll
            for (int j = 0; j < 4; j++) {
                int row = wn * 64 + j * 16 + l15;
                int ch = ((kk >> 3) + quad) ^ (row & 7);
                bn[j] = *(const bf16x8*)&Bs[row * 64 + ch * 8];
            }
#pragma unroll
            for (int i = 0; i < 4; i++)
#pragma unroll
                for (int j = 0; j < 4; j++)
                    acc[i][j] = __builtin_amdgcn_mfma_f32_16x16x32_bf16(am[i], bn[j], acc[i][j], 0, 0, 0);
        }
        __syncthreads();
    }

#pragma unroll
    for (int i = 0; i < 4; i++)
#pragma unroll
        for (int j = 0; j < 4; j++)
#pragma unroll
            for (int r = 0; r < 4; r++) {
                int mg = m0 + wm * 64 + i * 16 + quad * 4 + r;
                int ng = n0 + wn * 64 + j * 16 + l15;
                float v = acc[i][j][r];
                if (EPI == 0) {
                    int sel = ng >> 10, nl = ng & 1023, h = nl >> 6, d = nl & 63;
                    int b = mg >> 11, s = mg & 2047;
                    size_t idx = ((size_t)((b * NHEAD + h) * SEQ) + s) * HDIM + d;
                    if (sel == 0)      Qb[idx] = (bf16_t)(v * 0.125f);
                    else if (sel == 1) Kb[idx] = (bf16_t)v;
                    else               Vt[((size_t)((b * NHEAD + h) * HDIM) + d) * SEQ + s] = (bf16_t)v;
                } else {
                    Out[(size_t)mg * DMODEL + ng] = v + bo[ng];
                }
            }
}

// ---------------------------------------------------------------------------
// Attention v3: K/V tiles staged in LDS once per block (swizzled
// global_load_lds, double-buffered, prefetch before compute), XCD-aware task
// swizzle so each XCD's blocks cover 4 heads (2 MB K/V < 4 MB L2).
// No max-subtraction (scores bounded ~1.3); denominator via ones-MFMA.
// ---------------------------------------------------------------------------
__global__ __launch_bounds__(256) void attn_kernel(
    const bf16_t* __restrict__ Qb, const bf16_t* __restrict__ Kb,
    const bf16_t* __restrict__ Vt, bf16_t* __restrict__ ctx) {
    __shared__ __attribute__((aligned(16))) bf16_t Ks[2][64 * 64];
    __shared__ __attribute__((aligned(16))) bf16_t Vs[2][64 * 64];
    __shared__ __attribute__((aligned(16))) bf16_t Plds[4][16][72];
    const int tid = threadIdx.x;
    const int wave = tid >> 6, lane = tid & 63, quad = lane >> 4, l15 = lane & 15;

    // XCD-aware task swizzle: linear id % 8 picks XCD; give each XCD a
    // contiguous chunk of (b,h,qtile) space -> per-XCD K/V footprint 2 MB.
    const int id = blockIdx.x;
    const int task = (id & 7) * 128 + (id >> 3);
    const int b = task >> 9, h = (task >> 5) & 15, q0 = (task & 31) << 6;
    const int qbase = q0 + wave * 16;

    const bf16_t* Qp = Qb + (size_t)(b * NHEAD + h) * SEQ * HDIM;
    const bf16_t* Kp = Kb + (size_t)(b * NHEAD + h) * SEQ * HDIM;
    const bf16_t* Vp = Vt + (size_t)(b * NHEAD + h) * HDIM * SEQ;

    // Q A-fragments: lane holds Q[qbase + l15][quad*8 .. +8] (two 32-wide k chunks)
    bf16x8 qa0 = *(const bf16x8*)(Qp + (size_t)(qbase + l15) * HDIM + quad * 8);
    bf16x8 qa1 = *(const bf16x8*)(Qp + (size_t)(qbase + l15) * HDIM + 32 + quad * 8);

    bf16x8 ones;
#pragma unroll
    for (int j = 0; j < 8; j++) ones[j] = (bf16_t)1.0f;

    f32x4 O[4] = {};
    f32x4 lacc = {};

    const int qt = q0 >> 6;
    const int t0 = (qt - 4 > 0) ? qt - 4 : 0;
    const int t1 = (qt + 4 < SEQ / 64 - 1) ? qt + 4 : SEQ / 64 - 1;

    // stage K/V tile kt into buffer buf (512 swizzled 16B chunks each)
    auto stage = [&](int kt, int buf) {
        const int k0 = kt * 64;
#pragma unroll
        for (int i = 0; i < 2; i++) {
            int v = tid + i * 256;
            int row = v >> 3, c = (v & 7) ^ (row & 7);
            async_load16(Kp + (size_t)(k0 + row) * HDIM + c * 8, (char*)&Ks[buf][0] + (size_t)v * 16);
            async_load16(Vp + (size_t)row * SEQ + k0 + c * 8, (char*)&Vs[buf][0] + (size_t)v * 16);
        }
    };

    stage(t0, 0);
    int cb = 0;
    for (int kt = t0; kt <= t1; kt++) {
        __syncthreads();                       // current tile's staging complete
        if (kt < t1) stage(kt + 1, cb ^ 1);    // prefetch next (in flight during compute)
        const int k0 = kt * 64;
        f32x4 s[4];
#pragma unroll
        for (int c = 0; c < 4; c++) {
            int row = c * 16 + l15;
            bf16x8 kb0 = *(const bf16x8*)&Ks[cb][row * 64 + (quad ^ (row & 7)) * 8];
            bf16x8 kb1 = *(const bf16x8*)&Ks[cb][row * 64 + ((quad + 4) ^ (row & 7)) * 8];
            f32x4 a = {};
            a = __builtin_amdgcn_mfma_f32_16x16x32_bf16(qa0, kb0, a, 0, 0, 0);
            a = __builtin_amdgcn_mfma_f32_16x16x32_bf16(qa1, kb1, a, 0, 0, 0);
            s[c] = a;
        }
        // band mask — only |dt| == 4 tiles can contain out-of-window pairs
        const int dt = kt - qt;
        const bool edge = (dt <= -4 || dt >= 4);
#pragma unroll
        for (int c = 0; c < 4; c++)
#pragma unroll
            for (int r = 0; r < 4; r++) {
                float sv = s[c][r];
                if (edge) {
                    int i = qbase + quad * 4 + r;
                    int j = k0 + c * 16 + l15;
                    int dd = i - j; dd = (dd < 0) ? -dd : dd;
                    if (dd > WIN) sv = -1e30f;
                }
                Plds[wave][quad * 4 + r][c * 16 + l15] = (bf16_t)__expf(sv);
            }
        bf16x8 pa0 = *(const bf16x8*)&Plds[wave][l15][quad * 8];
        bf16x8 pa1 = *(const bf16x8*)&Plds[wave][l15][32 + quad * 8];
        lacc = __builtin_amdgcn_mfma_f32_16x16x32_bf16(pa0, ones, lacc, 0, 0, 0);
        lacc = __builtin_amdgcn_mfma_f32_16x16x32_bf16(pa1, ones, lacc, 0, 0, 0);
#pragma unroll
        for (int d = 0; d < 4; d++) {
            int row = d * 16 + l15;
            bf16x8 vb0 = *(const bf16x8*)&Vs[cb][row * 64 + (quad ^ (row & 7)) * 8];
            bf16x8 vb1 = *(const bf16x8*)&Vs[cb][row * 64 + ((quad + 4) ^ (row & 7)) * 8];
            O[d] = __builtin_amdgcn_mfma_f32_16x16x32_bf16(pa0, vb0, O[d], 0, 0, 0);
            O[d] = __builtin_amdgcn_mfma_f32_16x16x32_bf16(pa1, vb1, O[d], 0, 0, 0);
        }
        __syncthreads();                       // all waves done with cb before reuse
        cb ^= 1;
    }

#pragma unroll
    for (int r = 0; r < 4; r++) {
        float inv = 1.0f / lacc[r];
        int i = qbase + quad * 4 + r;
#pragma unroll
        for (int d = 0; d < 4; d++) {
            float v = O[d][r] * inv;
            ctx[((size_t)(b * SEQ + i)) * DMODEL + h * HDIM + d * 16 + l15] = (bf16_t)v;
        }
    }
}

// ---------------------------------------------------------------------------
extern "C" void kernel_launch(void* const* d_in, const int* in_sizes, int n_in,
                              void* d_out, int out_size, void* d_ws, size_t ws_size,
                              hipStream_t stream) {
    const float* x  = (const float*)d_in[0];
    const float* Wq = (const float*)d_in[1];
    const float* Wk = (const float*)d_in[2];
    const float* Wv = (const float*)d_in[3];
    const float* Wo = (const float*)d_in[4];
    const float* bo = (const float*)d_in[5];
    float* out = (float*)d_out;

    const size_t MTOK = (size_t)BATCH * SEQ;          // 4096
    bf16_t* xb  = (bf16_t*)d_ws;                      // 4096*1024
    bf16_t* Wt  = xb + MTOK * DMODEL;                 // 4*1024*1024 (q,k,v,o transposed)
    bf16_t* Qb  = Wt + (size_t)4 * DMODEL * DMODEL;   // [B,H,S,64]
    bf16_t* Kb  = Qb + MTOK * DMODEL;                 // [B,H,S,64]
    bf16_t* Vt  = Kb + MTOK * DMODEL;                 // [B,H,64,S]
    bf16_t* ctx = Vt + MTOK * DMODEL;                 // [4096][1024]

    cast_x_kernel<<<dim3((MTOK * DMODEL / 4 + 255) / 256), dim3(256), 0, stream>>>(
        x, xb, (int)(MTOK * DMODEL / 4));
    transpose_w_kernel<<<dim3(32, 32, 4), dim3(32, 8), 0, stream>>>(Wq, Wk, Wv, Wo, Wt);
    // QKV: M=4096, N=3072, K=1024
    gemm_bt_kernel<0><<<dim3(24, 32), dim3(256), 0, stream>>>(
        xb, Wt, Qb, Kb, Vt, nullptr, nullptr, DMODEL);
    attn_kernel<<<dim3(1024), dim3(256), 0, stream>>>(Qb, Kb, Vt, ctx);
    // Out: M=4096, N=1024, K=1024
    gemm_bt_kernel<1><<<dim3(8, 32), dim3(256), 0, stream>>>(
        ctx, Wt + (size_t)3 * DMODEL * DMODEL, nullptr, nullptr, nullptr, out, bo, DMODEL);
}

// Round 4
// 170.373 us; speedup vs baseline: 1.4176x; 1.0509x over previous
//
#include <hip/hip_runtime.h>
#include <hip/hip_bf16.h>

typedef __bf16 bf16_t;
typedef __bf16 bf16x8 __attribute__((ext_vector_type(8)));
typedef __bf16 bf16x4 __attribute__((ext_vector_type(4)));
typedef float  f32x4  __attribute__((ext_vector_type(4)));

#define SEQ    2048
#define BATCH  2
#define NHEAD  16
#define HDIM   64
#define DMODEL 1024
#define WIN    256

// async global->LDS, 16B per lane (dest = wave-uniform base + lane*16).
__device__ __forceinline__ void async_load16(const void* g, void* l) {
    __builtin_amdgcn_global_load_lds(
        (const __attribute__((address_space(1))) char*)(uintptr_t)g,
        (__attribute__((address_space(3))) char*)(uintptr_t)l, 16, 0, 0);
}

// ---------------------------------------------------------------------------
// Kernel 1: cast x (fp32) -> bf16, flat [4096][1024]
// ---------------------------------------------------------------------------
__global__ void cast_x_kernel(const float* __restrict__ x, bf16_t* __restrict__ xb, int n4) {
    int i = blockIdx.x * blockDim.x + threadIdx.x;
    if (i >= n4) return;
    float4 v = ((const float4*)x)[i];
    bf16x4 o;
    o[0] = (bf16_t)v.x; o[1] = (bf16_t)v.y; o[2] = (bf16_t)v.z; o[3] = (bf16_t)v.w;
    ((bf16x4*)xb)[i] = o;
}

// ---------------------------------------------------------------------------
// Kernel 2: transpose+cast weights into Wt[4][1024][1024] (B^T layout)
// ---------------------------------------------------------------------------
__global__ void transpose_w_kernel(const float* __restrict__ Wq, const float* __restrict__ Wk,
                                   const float* __restrict__ Wv, const float* __restrict__ Wo,
                                   bf16_t* __restrict__ Wt) {
    __shared__ float tile[32][33];
    const float* W = (blockIdx.z == 0) ? Wq : (blockIdx.z == 1) ? Wk : (blockIdx.z == 2) ? Wv : Wo;
    bf16_t* out = Wt + (size_t)blockIdx.z * DMODEL * DMODEL;
    int k0 = blockIdx.y * 32, n0 = blockIdx.x * 32;
    int tx = threadIdx.x, ty = threadIdx.y;  // block (32, 8)
#pragma unroll
    for (int i = 0; i < 4; i++)
        tile[ty + i * 8][tx] = W[(size_t)(k0 + ty + i * 8) * DMODEL + n0 + tx];
    __syncthreads();
#pragma unroll
    for (int i = 0; i < 4; i++)
        out[(size_t)(n0 + ty + i * 8) * DMODEL + k0 + tx] = (bf16_t)tile[tx][ty + i * 8];
}

// ---------------------------------------------------------------------------
// Kernel 3: V transpose, Vb[B,H,S,64] -> Vt[B,H,64,S]. Block (64,4), 64x64 tile.
// ---------------------------------------------------------------------------
__global__ __launch_bounds__(256) void vtrans_kernel(const bf16_t* __restrict__ Vb,
                                                     bf16_t* __restrict__ Vt) {
    __shared__ bf16_t tile[64][65];
    const int bh = blockIdx.y, s0 = blockIdx.x * 64;
    const int tx = threadIdx.x, ty = threadIdx.y;
    const bf16_t* src = Vb + ((size_t)bh * SEQ + s0) * HDIM;
    bf16_t* dst = Vt + (size_t)bh * HDIM * SEQ + s0;
#pragma unroll
    for (int i = 0; i < 16; i++) {
        int row = i * 4 + ty;
        tile[row][tx] = src[(size_t)row * HDIM + tx];      // coalesced 128B/wave
    }
    __syncthreads();
#pragma unroll
    for (int i = 0; i < 16; i++) {
        int d = i * 4 + ty;
        dst[(size_t)d * SEQ + tx] = tile[tx][d];           // coalesced 128B/wave
    }
}

// ---------------------------------------------------------------------------
// GEMM: C = A * Bt^T, 128x128 tile, swizzled global_load_lds staging,
// 1D grid with XCD-aware (n-strip per XCD) decomposition.
// EPI 0: QKV epilogue -> Qb(scaled)/Kb/Vb all [B,H,S,64] coalesced.
// EPI 1: Out = acc + bo (fp32).
// ---------------------------------------------------------------------------
template <int EPI>
__global__ __launch_bounds__(256) void gemm_bt_kernel(
    const bf16_t* __restrict__ A, const bf16_t* __restrict__ Bt,
    bf16_t* __restrict__ Qb, bf16_t* __restrict__ Kb, bf16_t* __restrict__ Vb,
    float* __restrict__ Out, const float* __restrict__ bo, int K, int nPer) {
    __shared__ __attribute__((aligned(16))) bf16_t As[128 * 64];
    __shared__ __attribute__((aligned(16))) bf16_t Bs[128 * 64];
    const int tid = threadIdx.x;
    const int wave = tid >> 6, lane = tid & 63, quad = lane >> 4, l15 = lane & 15;
    const int wm = wave >> 1, wn = wave & 1;
    // XCD swizzle: id&7 = XCD; each XCD owns an nPer-wide n-strip, m varies inside.
    const int id = blockIdx.x, xcd = id & 7, t = id >> 3;
    const int m0 = (t / nPer) * 128, n0 = (xcd * nPer + t % nPer) * 128;

    f32x4 acc[4][4] = {};

    for (int kt = 0; kt < K; kt += 64) {
#pragma unroll
        for (int i = 0; i < 4; i++) {
            int v = tid + i * 256;           // 1024 chunks of 16B per matrix
            int row = v >> 3, c = (v & 7) ^ (row & 7);
            async_load16(A + (size_t)(m0 + row) * K + kt + c * 8, (char*)As + (size_t)v * 16);
            async_load16(Bt + (size_t)(n0 + row) * K + kt + c * 8, (char*)Bs + (size_t)v * 16);
        }
        __syncthreads();
#pragma unroll
        for (int kk = 0; kk < 64; kk += 32) {
            bf16x8 am[4], bn[4];
#pragma unroll
            for (int i = 0; i < 4; i++) {
                int row = wm * 64 + i * 16 + l15;
                int ch = ((kk >> 3) + quad) ^ (row & 7);
                am[i] = *(const bf16x8*)&As[row * 64 + ch * 8];
            }
#pragma unroll
            for (int j = 0; j < 4; j++) {
                int row = wn * 64 + j * 16 + l15;
                int ch = ((kk >> 3) + quad) ^ (row & 7);
                bn[j] = *(const bf16x8*)&Bs[row * 64 + ch * 8];
            }
#pragma unroll
            for (int i = 0; i < 4; i++)
#pragma unroll
                for (int j = 0; j < 4; j++)
                    acc[i][j] = __builtin_amdgcn_mfma_f32_16x16x32_bf16(am[i], bn[j], acc[i][j], 0, 0, 0);
        }
        __syncthreads();
    }

#pragma unroll
    for (int i = 0; i < 4; i++)
#pragma unroll
        for (int j = 0; j < 4; j++)
#pragma unroll
            for (int r = 0; r < 4; r++) {
                int mg = m0 + wm * 64 + i * 16 + quad * 4 + r;
                int ng = n0 + wn * 64 + j * 16 + l15;
                float v = acc[i][j][r];
                if (EPI == 0) {
                    int sel = ng >> 10, nl = ng & 1023, h = nl >> 6, d = nl & 63;
                    int b = mg >> 11, s = mg & 2047;
                    size_t idx = ((size_t)((b * NHEAD + h) * SEQ) + s) * HDIM + d;
                    if (sel == 0)      Qb[idx] = (bf16_t)(v * 0.125f);
                    else if (sel == 1) Kb[idx] = (bf16_t)v;
                    else               Vb[idx] = (bf16_t)v;
                } else {
                    Out[(size_t)mg * DMODEL + ng] = v + bo[ng];
                }
            }
}

// ---------------------------------------------------------------------------
// Attention v4: 512 threads, 2 query-tiles (128 queries) per block; waves 0-3
// own qtile A rows, waves 4-7 qtile A+1. Block stages the union window (10
// K/V tiles), each wave computes only its own 9 in-window tiles. Double-
// buffered swizzled global_load_lds staging; XCD-aware task swizzle (4 heads
// per XCD -> 2 MB K/V per XCD L2). exp without max (scores bounded ~1.3);
// denominator via ones-MFMA row sum.
// ---------------------------------------------------------------------------
__global__ __launch_bounds__(512) void attn_kernel(
    const bf16_t* __restrict__ Qb, const bf16_t* __restrict__ Kb,
    const bf16_t* __restrict__ Vt, bf16_t* __restrict__ ctx) {
    __shared__ __attribute__((aligned(16))) bf16_t Ks[2][64 * 64];
    __shared__ __attribute__((aligned(16))) bf16_t Vs[2][64 * 64];
    __shared__ __attribute__((aligned(16))) bf16_t Plds[8][16][72];
    const int tid = threadIdx.x;
    const int wave = tid >> 6, lane = tid & 63, quad = lane >> 4, l15 = lane & 15;

    // 512 blocks; XCD gets 64 consecutive tasks = 4 heads x 16 query-pairs.
    const int id = blockIdx.x;
    const int task = (id & 7) * 64 + (id >> 3);
    const int b = task >> 8, h = (task >> 4) & 15, Q0 = (task & 15) << 7;
    const int qbase = Q0 + wave * 16;
    const int wqt = (Q0 >> 6) + (wave >> 2);   // this wave's 64-aligned q-tile

    const bf16_t* Qp = Qb + (size_t)(b * NHEAD + h) * SEQ * HDIM;
    const bf16_t* Kp = Kb + (size_t)(b * NHEAD + h) * SEQ * HDIM;
    const bf16_t* Vp = Vt + (size_t)(b * NHEAD + h) * HDIM * SEQ;

    bf16x8 qa0 = *(const bf16x8*)(Qp + (size_t)(qbase + l15) * HDIM + quad * 8);
    bf16x8 qa1 = *(const bf16x8*)(Qp + (size_t)(qbase + l15) * HDIM + 32 + quad * 8);

    bf16x8 ones;
#pragma unroll
    for (int j = 0; j < 8; j++) ones[j] = (bf16_t)1.0f;

    f32x4 O[4] = {};
    f32x4 lacc = {};

    const int base_t = Q0 >> 6;
    const int bt0 = (base_t - 4 > 0) ? base_t - 4 : 0;
    const int bt1 = (base_t + 5 < SEQ / 64 - 1) ? base_t + 5 : SEQ / 64 - 1;

    auto stage = [&](int kt, int buf) {
        const int k0 = kt * 64;
        int v = tid;                          // 512 chunks of 16B each
        int row = v >> 3, c = (v & 7) ^ (row & 7);
        async_load16(Kp + (size_t)(k0 + row) * HDIM + c * 8, (char*)&Ks[buf][0] + (size_t)v * 16);
        async_load16(Vp + (size_t)row * SEQ + k0 + c * 8, (char*)&Vs[buf][0] + (size_t)v * 16);
    };

    stage(bt0, 0);
    int cb = 0;
    for (int kt = bt0; kt <= bt1; kt++) {
        __syncthreads();                       // staging of current tile complete
        if (kt < bt1) stage(kt + 1, cb ^ 1);   // prefetch next during compute
        const int dt = kt - wqt;
        if (dt >= -4 && dt <= 4) {             // wave-uniform window check
            const int k0 = kt * 64;
            f32x4 s[4];
#pragma unroll
            for (int c = 0; c < 4; c++) {
                int row = c * 16 + l15;
                bf16x8 kb0 = *(const bf16x8*)&Ks[cb][row * 64 + (quad ^ (row & 7)) * 8];
                bf16x8 kb1 = *(const bf16x8*)&Ks[cb][row * 64 + ((quad + 4) ^ (row & 7)) * 8];
                f32x4 a = {};
                a = __builtin_amdgcn_mfma_f32_16x16x32_bf16(qa0, kb0, a, 0, 0, 0);
                a = __builtin_amdgcn_mfma_f32_16x16x32_bf16(qa1, kb1, a, 0, 0, 0);
                s[c] = a;
            }
            const bool edge = (dt == -4 || dt == 4);
#pragma unroll
            for (int c = 0; c < 4; c++)
#pragma unroll
                for (int r = 0; r < 4; r++) {
                    float sv = s[c][r];
                    if (edge) {
                        int i = qbase + quad * 4 + r;
                        int j = k0 + c * 16 + l15;
                        int dd = i - j; dd = (dd < 0) ? -dd : dd;
                        if (dd > WIN) sv = -1e30f;
                    }
                    Plds[wave][quad * 4 + r][c * 16 + l15] = (bf16_t)__expf(sv);
                }
            bf16x8 pa0 = *(const bf16x8*)&Plds[wave][l15][quad * 8];
            bf16x8 pa1 = *(const bf16x8*)&Plds[wave][l15][32 + quad * 8];
            lacc = __builtin_amdgcn_mfma_f32_16x16x32_bf16(pa0, ones, lacc, 0, 0, 0);
            lacc = __builtin_amdgcn_mfma_f32_16x16x32_bf16(pa1, ones, lacc, 0, 0, 0);
#pragma unroll
            for (int d = 0; d < 4; d++) {
                int row = d * 16 + l15;
                bf16x8 vb0 = *(const bf16x8*)&Vs[cb][row * 64 + (quad ^ (row & 7)) * 8];
                bf16x8 vb1 = *(const bf16x8*)&Vs[cb][row * 64 + ((quad + 4) ^ (row & 7)) * 8];
                O[d] = __builtin_amdgcn_mfma_f32_16x16x32_bf16(pa0, vb0, O[d], 0, 0, 0);
                O[d] = __builtin_amdgcn_mfma_f32_16x16x32_bf16(pa1, vb1, O[d], 0, 0, 0);
            }
        }
        __syncthreads();                       // all waves done with cb before reuse
        cb ^= 1;
    }

#pragma unroll
    for (int r = 0; r < 4; r++) {
        float inv = 1.0f / lacc[r];
        int i = qbase + quad * 4 + r;
#pragma unroll
        for (int d = 0; d < 4; d++) {
            float v = O[d][r] * inv;
            ctx[((size_t)(b * SEQ + i)) * DMODEL + h * HDIM + d * 16 + l15] = (bf16_t)v;
        }
    }
}

// ---------------------------------------------------------------------------
extern "C" void kernel_launch(void* const* d_in, const int* in_sizes, int n_in,
                              void* d_out, int out_size, void* d_ws, size_t ws_size,
                              hipStream_t stream) {
    const float* x  = (const float*)d_in[0];
    const float* Wq = (const float*)d_in[1];
    const float* Wk = (const float*)d_in[2];
    const float* Wv = (const float*)d_in[3];
    const float* Wo = (const float*)d_in[4];
    const float* bo = (const float*)d_in[5];
    float* out = (float*)d_out;

    const size_t MTOK = (size_t)BATCH * SEQ;          // 4096
    bf16_t* xb  = (bf16_t*)d_ws;                      // 4096*1024
    bf16_t* Wt  = xb + MTOK * DMODEL;                 // 4*1024*1024
    bf16_t* Qb  = Wt + (size_t)4 * DMODEL * DMODEL;   // [B,H,S,64]
    bf16_t* Kb  = Qb + MTOK * DMODEL;                 // [B,H,S,64]
    bf16_t* Vt  = Kb + MTOK * DMODEL;                 // [B,H,64,S]
    bf16_t* ctx = Vt + MTOK * DMODEL;                 // [4096][1024]
    bf16_t* Vb  = ctx;  // alias: Vb dead before attn writes ctx

    cast_x_kernel<<<dim3((MTOK * DMODEL / 4 + 255) / 256), dim3(256), 0, stream>>>(
        x, xb, (int)(MTOK * DMODEL / 4));
    transpose_w_kernel<<<dim3(32, 32, 4), dim3(32, 8), 0, stream>>>(Wq, Wk, Wv, Wo, Wt);
    // QKV: M=4096, N=3072, K=1024; 768 blocks, 3 n-strips per XCD
    gemm_bt_kernel<0><<<dim3(768), dim3(256), 0, stream>>>(
        xb, Wt, Qb, Kb, Vb, nullptr, nullptr, DMODEL, 3);
    vtrans_kernel<<<dim3(32, 32), dim3(64, 4), 0, stream>>>(Vb, Vt);
    attn_kernel<<<dim3(512), dim3(512), 0, stream>>>(Qb, Kb, Vt, ctx);
    // Out: M=4096, N=1024, K=1024; 256 blocks, 1 n-strip per XCD
    gemm_bt_kernel<1><<<dim3(256), dim3(256), 0, stream>>>(
        ctx, Wt + (size_t)3 * DMODEL * DMODEL, nullptr, nullptr, nullptr, out, bo, DMODEL, 1);
}